// Round 1
// baseline (2110.577 us; speedup 1.0000x reference)
//
#include <hip/hip_runtime.h>

// Problem constants
#define BB 4
#define LL 1024
#define CC 768
#define HH 12
#define DD 64   // head dim

// ---------------- GEMM: out = A[M x K] @ W[K x N] (row-major) ----------------
// BM=BN=64, BK=16, 256 threads, 4x4 microtile per thread.
// qkv_mode==1: write to [b][h][l][d] layout (row = b*1024+l, col = h*64+d)
#define Bb_M 64
#define Bb_N 64
#define Bb_K 16

__global__ __launch_bounds__(256) void gemm64(const float* __restrict__ A,
                                              const float* __restrict__ W,
                                              float* __restrict__ out,
                                              int M, int K, int N,
                                              float scale, int qkv_mode) {
    __shared__ float As[Bb_K][Bb_M + 4];  // +4 keeps float4 alignment, 2-way bank alias only
    __shared__ float Bs[Bb_K][Bb_N + 4];

    const int tid = threadIdx.x;
    const int bm = blockIdx.x * Bb_M;
    const int bn = blockIdx.y * Bb_N;
    const int tx = tid & 15;   // 0..15
    const int ty = tid >> 4;   // 0..15

    float acc[4][4] = {};

    for (int k0 = 0; k0 < K; k0 += Bb_K) {
        // Load A tile (64 rows x 16 cols), transposed into As[k][m]
        {
            int c = tid & 15;      // k within tile
            int r = tid >> 4;      // row base
#pragma unroll
            for (int rr = 0; rr < 4; ++rr) {
                As[c][r + rr * 16] = A[(size_t)(bm + r + rr * 16) * K + k0 + c];
            }
        }
        // Load B tile (16 rows x 64 cols)
        {
            int c = tid & 63;
            int r = tid >> 6;
#pragma unroll
            for (int rr = 0; rr < 4; ++rr) {
                Bs[r + rr * 4][c] = W[(size_t)(k0 + r + rr * 4) * N + bn + c];
            }
        }
        __syncthreads();

#pragma unroll
        for (int kk = 0; kk < Bb_K; ++kk) {
            float a[4], b[4];
#pragma unroll
            for (int i = 0; i < 4; ++i) a[i] = As[kk][ty * 4 + i];
#pragma unroll
            for (int j = 0; j < 4; ++j) b[j] = Bs[kk][tx * 4 + j];
#pragma unroll
            for (int i = 0; i < 4; ++i)
#pragma unroll
                for (int j = 0; j < 4; ++j)
                    acc[i][j] += a[i] * b[j];
        }
        __syncthreads();
    }

#pragma unroll
    for (int i = 0; i < 4; ++i) {
        int row = bm + ty * 4 + i;
#pragma unroll
        for (int j = 0; j < 4; ++j) {
            int col = bn + tx * 4 + j;
            float v = acc[i][j] * scale;
            if (qkv_mode) {
                int b = row >> 10, l = row & 1023;
                int h = col >> 6, d = col & 63;
                out[((size_t)(b * HH + h) * LL + l) * DD + d] = v;
            } else {
                out[(size_t)row * N + col] = v;
            }
        }
    }
}

// ---------------- Attention core: one block per (b, l) row ----------------
// LDS: full logits row s[12][1024] (48 KB). Steps:
//  1) raw logits s[h][k] = q[h,:]·K[h,k,:]
//  2) pre-mix across heads (W_pre)
//  3) per-head softmax over k (wave-level reduction, 4 waves x 3 heads)
//  4) post-mix across heads (W_post)
//  5) O[i,d] = sum_k s[i][k] * V[i,k,d]; write att[b*L+l][i*64+d]
__global__ __launch_bounds__(256) void attn_core(const float* __restrict__ Q,
                                                 const float* __restrict__ K,
                                                 const float* __restrict__ V,
                                                 const float* __restrict__ Wpre,
                                                 const float* __restrict__ Wpost,
                                                 float* __restrict__ att) {
    __shared__ float s[HH][LL];        // 48 KB
    __shared__ float qs[HH][DD];       // 3 KB
    __shared__ float wpre[HH][HH];
    __shared__ float wpost[HH][HH];

    const int tid = threadIdx.x;
    // b in low bits: each XCD (blockIdx % 8 round-robin) serves one batch's K/V in L2
    const int b = blockIdx.x & 3;
    const int l = blockIdx.x >> 2;

    if (tid < HH * HH) {
        wpre[tid / HH][tid % HH] = Wpre[tid];
        wpost[tid / HH][tid % HH] = Wpost[tid];
    }
    for (int idx = tid; idx < HH * DD; idx += 256) {
        int h = idx >> 6, d = idx & 63;
        qs[h][d] = Q[((size_t)(b * HH + h) * LL + l) * DD + d];
    }
    __syncthreads();

    // ---- step 1: raw logits ----
    for (int idx = tid; idx < HH * LL; idx += 256) {
        int h = idx >> 10, k = idx & 1023;
        const float4* kp4 = (const float4*)(K + ((size_t)(b * HH + h) * LL + k) * DD);
        const float4* qp4 = (const float4*)(qs[h]);
        float ax = 0.f, ay = 0.f, az = 0.f, aw = 0.f;
#pragma unroll
        for (int d4 = 0; d4 < 16; ++d4) {
            float4 kv = kp4[d4];
            float4 qv = qp4[d4];
            ax += qv.x * kv.x; ay += qv.y * kv.y;
            az += qv.z * kv.z; aw += qv.w * kv.w;
        }
        s[h][k] = (ax + ay) + (az + aw);
    }
    __syncthreads();

    // ---- step 2: pre-softmax head mixing ----
    for (int k = tid; k < LL; k += 256) {
        float sv[HH], mx[HH];
#pragma unroll
        for (int h = 0; h < HH; ++h) sv[h] = s[h][k];
#pragma unroll
        for (int i = 0; i < HH; ++i) {
            float a = 0.f;
#pragma unroll
            for (int h = 0; h < HH; ++h) a += sv[h] * wpre[h][i];
            mx[i] = a;
        }
#pragma unroll
        for (int i = 0; i < HH; ++i) s[i][k] = mx[i];
    }
    __syncthreads();

    // ---- step 3: per-head softmax over k ----
    {
        const int wave = tid >> 6;
        const int lane = tid & 63;
        for (int h = wave; h < HH; h += 4) {
            float vals[16];
            float m = -1e30f;
#pragma unroll
            for (int j = 0; j < 16; ++j) {
                vals[j] = s[h][lane + 64 * j];
                m = fmaxf(m, vals[j]);
            }
#pragma unroll
            for (int off = 32; off; off >>= 1) m = fmaxf(m, __shfl_xor(m, off));
            float sum = 0.f;
#pragma unroll
            for (int j = 0; j < 16; ++j) {
                vals[j] = __expf(vals[j] - m);
                sum += vals[j];
            }
#pragma unroll
            for (int off = 32; off; off >>= 1) sum += __shfl_xor(sum, off);
            float inv = 1.0f / sum;
#pragma unroll
            for (int j = 0; j < 16; ++j) s[h][lane + 64 * j] = vals[j] * inv;
        }
    }
    __syncthreads();

    // ---- step 4: post-softmax head mixing ----
    for (int k = tid; k < LL; k += 256) {
        float sv[HH], mx[HH];
#pragma unroll
        for (int h = 0; h < HH; ++h) sv[h] = s[h][k];
#pragma unroll
        for (int i = 0; i < HH; ++i) {
            float a = 0.f;
#pragma unroll
            for (int h = 0; h < HH; ++h) a += sv[h] * wpost[h][i];
            mx[i] = a;
        }
#pragma unroll
        for (int i = 0; i < HH; ++i) s[i][k] = mx[i];
    }
    __syncthreads();

    // ---- step 5: O = W @ V, write att row ----
    {
        const int i0 = tid >> 6;   // 0..3
        const int d0 = tid & 63;
        float o0 = 0.f, o1 = 0.f, o2 = 0.f;
        const float* vb = V + (size_t)b * HH * LL * DD;
        const float* v0 = vb + ((size_t)(i0 + 0) * LL) * DD + d0;
        const float* v1 = vb + ((size_t)(i0 + 4) * LL) * DD + d0;
        const float* v2 = vb + ((size_t)(i0 + 8) * LL) * DD + d0;
#pragma unroll 4
        for (int k = 0; k < LL; ++k) {
            o0 += s[i0 + 0][k] * v0[(size_t)k * DD];
            o1 += s[i0 + 4][k] * v1[(size_t)k * DD];
            o2 += s[i0 + 8][k] * v2[(size_t)k * DD];
        }
        float* arow = att + (size_t)(b * LL + l) * CC;
        arow[(i0 + 0) * DD + d0] = o0;
        arow[(i0 + 4) * DD + d0] = o1;
        arow[(i0 + 8) * DD + d0] = o2;
    }
}

// ---------------- Launch ----------------
extern "C" void kernel_launch(void* const* d_in, const int* in_sizes, int n_in,
                              void* d_out, int out_size, void* d_ws, size_t ws_size,
                              hipStream_t stream) {
    const float* inputs_q  = (const float*)d_in[0];
    const float* inputs_kv = (const float*)d_in[1];
    const float* Wq   = (const float*)d_in[2];
    const float* Wk   = (const float*)d_in[3];
    const float* Wv   = (const float*)d_in[4];
    const float* Wout = (const float*)d_in[5];
    const float* Wpre  = (const float*)d_in[6];
    const float* Wpost = (const float*)d_in[7];
    float* out = (float*)d_out;

    const size_t nQKV = (size_t)BB * HH * LL * DD;   // 3,145,728 floats
    float* Qb  = (float*)d_ws;
    float* Kb  = Qb + nQKV;
    float* Vb  = Kb + nQKV;
    float* Att = Vb + nQKV;                           // [B*L][C]

    const int M = BB * LL;   // 4096
    const int Kdim = CC;     // 768
    const int N = HH * DD;   // 768

    dim3 grid(M / Bb_M, N / Bb_N);
    dim3 blk(256);

    const float qscale = 0.125f;  // 1/sqrt(64)
    gemm64<<<grid, blk, 0, stream>>>(inputs_q,  Wq, Qb, M, Kdim, N, qscale, 1);
    gemm64<<<grid, blk, 0, stream>>>(inputs_kv, Wk, Kb, M, Kdim, N, 1.0f, 1);
    gemm64<<<grid, blk, 0, stream>>>(inputs_kv, Wv, Vb, M, Kdim, N, 1.0f, 1);

    attn_core<<<dim3(BB * LL), blk, 0, stream>>>(Qb, Kb, Vb, Wpre, Wpost, Att);

    gemm64<<<grid, blk, 0, stream>>>(Att, Wout, out, M, Kdim, CC, 1.0f, 0);
}

// Round 2
// 675.439 us; speedup vs baseline: 3.1247x; 3.1247x over previous
//
#include <hip/hip_runtime.h>

// Problem constants
#define BB 4
#define LL 1024
#define CC 768
#define HH 12
#define DD 64   // head dim

// ---------------- GEMM: out = A[M x K] @ W[K x N] (row-major) ----------------
// BM=BN=64, BK=16, 256 threads, 4x4 microtile per thread.
// qkv_mode==1: write to [b][h][l][d] layout (row = b*1024+l, col = h*64+d)
#define Bb_M 64
#define Bb_N 64
#define Bb_K 16

__global__ __launch_bounds__(256) void gemm64(const float* __restrict__ A,
                                              const float* __restrict__ W,
                                              float* __restrict__ out,
                                              int M, int K, int N,
                                              float scale, int qkv_mode) {
    __shared__ float As[Bb_K][Bb_M + 4];
    __shared__ float Bs[Bb_K][Bb_N + 4];

    const int tid = threadIdx.x;
    const int bm = blockIdx.x * Bb_M;
    const int bn = blockIdx.y * Bb_N;
    const int tx = tid & 15;   // 0..15
    const int ty = tid >> 4;   // 0..15

    float acc[4][4] = {};

    for (int k0 = 0; k0 < K; k0 += Bb_K) {
        {
            int c = tid & 15;
            int r = tid >> 4;
#pragma unroll
            for (int rr = 0; rr < 4; ++rr) {
                As[c][r + rr * 16] = A[(size_t)(bm + r + rr * 16) * K + k0 + c];
            }
        }
        {
            int c = tid & 63;
            int r = tid >> 6;
#pragma unroll
            for (int rr = 0; rr < 4; ++rr) {
                Bs[r + rr * 4][c] = W[(size_t)(k0 + r + rr * 4) * N + bn + c];
            }
        }
        __syncthreads();

#pragma unroll
        for (int kk = 0; kk < Bb_K; ++kk) {
            float a[4], b[4];
#pragma unroll
            for (int i = 0; i < 4; ++i) a[i] = As[kk][ty * 4 + i];
#pragma unroll
            for (int j = 0; j < 4; ++j) b[j] = Bs[kk][tx * 4 + j];
#pragma unroll
            for (int i = 0; i < 4; ++i)
#pragma unroll
                for (int j = 0; j < 4; ++j)
                    acc[i][j] += a[i] * b[j];
        }
        __syncthreads();
    }

#pragma unroll
    for (int i = 0; i < 4; ++i) {
        int row = bm + ty * 4 + i;
#pragma unroll
        for (int j = 0; j < 4; ++j) {
            int col = bn + tx * 4 + j;
            float v = acc[i][j] * scale;
            if (qkv_mode) {
                int b = row >> 10, l = row & 1023;
                int h = col >> 6, d = col & 63;
                out[((size_t)(b * HH + h) * LL + l) * DD + d] = v;
            } else {
                out[(size_t)row * N + col] = v;
            }
        }
    }
}

// ---------------- K1: raw logits S[bh][l][k] = Q[bh,l,:]·K[bh,k,:] ----------------
// grid (16 l-tiles, 16 k-tiles, n_bh). Both A and B tiles loaded transposed [d][row].
__global__ __launch_bounds__(256) void qk_gemm(const float* __restrict__ Q,
                                               const float* __restrict__ Km,
                                               float* __restrict__ S) {
    __shared__ float As[16][68];
    __shared__ float Bs[16][68];
    const int tid = threadIdx.x;
    const int bm = blockIdx.x * 64;
    const int bn = blockIdx.y * 64;
    const int bh = blockIdx.z;
    const float* Qh = Q + (size_t)bh * LL * DD;
    const float* Kh = Km + (size_t)bh * LL * DD;
    const int tx = tid & 15, ty = tid >> 4;

    float acc[4][4] = {};

    for (int k0 = 0; k0 < DD; k0 += 16) {
        int c = tid & 15;   // d within tile
        int r = tid >> 4;
#pragma unroll
        for (int rr = 0; rr < 4; ++rr)
            As[c][r + rr * 16] = Qh[(size_t)(bm + r + rr * 16) * DD + k0 + c];
#pragma unroll
        for (int rr = 0; rr < 4; ++rr)
            Bs[c][r + rr * 16] = Kh[(size_t)(bn + r + rr * 16) * DD + k0 + c];
        __syncthreads();

#pragma unroll
        for (int kk = 0; kk < 16; ++kk) {
            float a[4], b[4];
#pragma unroll
            for (int i = 0; i < 4; ++i) a[i] = As[kk][ty * 4 + i];
#pragma unroll
            for (int j = 0; j < 4; ++j) b[j] = Bs[kk][tx * 4 + j];
#pragma unroll
            for (int i = 0; i < 4; ++i)
#pragma unroll
                for (int j = 0; j < 4; ++j)
                    acc[i][j] += a[i] * b[j];
        }
        __syncthreads();
    }

#pragma unroll
    for (int i = 0; i < 4; ++i) {
        float4 v = make_float4(acc[i][0], acc[i][1], acc[i][2], acc[i][3]);
        *(float4*)&S[((size_t)bh * LL + bm + ty * 4 + i) * LL + bn + tx * 4] = v;
    }
}

// ---------------- K2: per (b,l) row: premix -> softmax -> postmix, in-place ----------------
__global__ __launch_bounds__(256) void mix_softmax(float* __restrict__ S,
                                                   const float* __restrict__ Wpre,
                                                   const float* __restrict__ Wpost) {
    __shared__ float s[HH][LL];        // 48 KB
    __shared__ float wpre[HH][HH];
    __shared__ float wpost[HH][HH];

    const int tid = threadIdx.x;
    const int l = blockIdx.x;
    const int b = blockIdx.y;

    if (tid < HH * HH) {
        wpre[tid / HH][tid % HH] = Wpre[tid];
        wpost[tid / HH][tid % HH] = Wpost[tid];
    }

    // load all 12 head rows, vectorized
    for (int idx = tid; idx < HH * LL / 4; idx += 256) {
        int h = idx >> 8;        // 256 float4 per row
        int k4 = idx & 255;
        ((float4*)s[h])[k4] =
            *(const float4*)(S + ((size_t)(b * HH + h) * LL + l) * LL + (size_t)k4 * 4);
    }
    __syncthreads();

    // premix across heads
    for (int k = tid; k < LL; k += 256) {
        float sv[HH], mx[HH];
#pragma unroll
        for (int h = 0; h < HH; ++h) sv[h] = s[h][k];
#pragma unroll
        for (int i = 0; i < HH; ++i) {
            float a = 0.f;
#pragma unroll
            for (int h = 0; h < HH; ++h) a += sv[h] * wpre[h][i];
            mx[i] = a;
        }
#pragma unroll
        for (int i = 0; i < HH; ++i) s[i][k] = mx[i];
    }
    __syncthreads();

    // per-head softmax over k
    {
        const int wave = tid >> 6;
        const int lane = tid & 63;
        for (int h = wave; h < HH; h += 4) {
            float vals[16];
            float m = -1e30f;
#pragma unroll
            for (int j = 0; j < 16; ++j) {
                vals[j] = s[h][lane + 64 * j];
                m = fmaxf(m, vals[j]);
            }
#pragma unroll
            for (int off = 32; off; off >>= 1) m = fmaxf(m, __shfl_xor(m, off));
            float sum = 0.f;
#pragma unroll
            for (int j = 0; j < 16; ++j) {
                vals[j] = __expf(vals[j] - m);
                sum += vals[j];
            }
#pragma unroll
            for (int off = 32; off; off >>= 1) sum += __shfl_xor(sum, off);
            float inv = 1.0f / sum;
#pragma unroll
            for (int j = 0; j < 16; ++j) s[h][lane + 64 * j] = vals[j] * inv;
        }
    }
    __syncthreads();

    // postmix across heads
    for (int k = tid; k < LL; k += 256) {
        float sv[HH], mx[HH];
#pragma unroll
        for (int h = 0; h < HH; ++h) sv[h] = s[h][k];
#pragma unroll
        for (int i = 0; i < HH; ++i) {
            float a = 0.f;
#pragma unroll
            for (int h = 0; h < HH; ++h) a += sv[h] * wpost[h][i];
            mx[i] = a;
        }
#pragma unroll
        for (int i = 0; i < HH; ++i) s[i][k] = mx[i];
    }
    __syncthreads();

    // store back (same addresses, safe: everything staged in LDS)
    for (int idx = tid; idx < HH * LL / 4; idx += 256) {
        int i = idx >> 8;
        int k4 = idx & 255;
        *(float4*)(S + ((size_t)(b * HH + i) * LL + l) * LL + (size_t)k4 * 4) =
            ((float4*)s[i])[k4];
    }
}

// ---------------- K3: att[b,l,i*64+d] = sum_k Wt[bh,l,k] * V[bh,k,d] ----------------
// grid (16 m-tiles, n_bh). BM=64, BN=64(=DD), BK=16.
__global__ __launch_bounds__(256) void pv_gemm(const float* __restrict__ Wt,
                                               const float* __restrict__ V,
                                               float* __restrict__ att) {
    __shared__ float As[16][68];   // Wt tile transposed [k][l]
    __shared__ float Bs[16][68];   // V tile [k][d]
    const int tid = threadIdx.x;
    const int bm = blockIdx.x * 64;
    const int bh = blockIdx.y;
    const int b = bh / HH;
    const int ih = bh % HH;
    const float* A = Wt + (size_t)bh * LL * LL;
    const float* Bv = V + (size_t)bh * LL * DD;
    const int tx = tid & 15, ty = tid >> 4;

    float acc[4][4] = {};

    for (int k0 = 0; k0 < LL; k0 += 16) {
        {
            int c = tid & 15;   // k within tile
            int r = tid >> 4;
#pragma unroll
            for (int rr = 0; rr < 4; ++rr)
                As[c][r + rr * 16] = A[(size_t)(bm + r + rr * 16) * LL + k0 + c];
        }
        {
            int c = tid & 63;   // d
            int r = tid >> 6;
#pragma unroll
            for (int rr = 0; rr < 4; ++rr)
                Bs[r + rr * 4][c] = Bv[(size_t)(k0 + r + rr * 4) * DD + c];
        }
        __syncthreads();

#pragma unroll
        for (int kk = 0; kk < 16; ++kk) {
            float a[4], bb[4];
#pragma unroll
            for (int i = 0; i < 4; ++i) a[i] = As[kk][ty * 4 + i];
#pragma unroll
            for (int j = 0; j < 4; ++j) bb[j] = Bs[kk][tx * 4 + j];
#pragma unroll
            for (int i = 0; i < 4; ++i)
#pragma unroll
                for (int j = 0; j < 4; ++j)
                    acc[i][j] += a[i] * bb[j];
        }
        __syncthreads();
    }

#pragma unroll
    for (int i = 0; i < 4; ++i) {
        float4 v = make_float4(acc[i][0], acc[i][1], acc[i][2], acc[i][3]);
        *(float4*)&att[((size_t)(b * LL) + bm + ty * 4 + i) * CC + ih * DD + tx * 4] = v;
    }
}

// ---------------- Fallback (round-1 attn_core), used only if ws is tiny ----------------
__global__ __launch_bounds__(256) void attn_core(const float* __restrict__ Q,
                                                 const float* __restrict__ K,
                                                 const float* __restrict__ V,
                                                 const float* __restrict__ Wpre,
                                                 const float* __restrict__ Wpost,
                                                 float* __restrict__ att) {
    __shared__ float s[HH][LL];
    __shared__ float qs[HH][DD];
    __shared__ float wpre[HH][HH];
    __shared__ float wpost[HH][HH];

    const int tid = threadIdx.x;
    const int b = blockIdx.x & 3;
    const int l = blockIdx.x >> 2;

    if (tid < HH * HH) {
        wpre[tid / HH][tid % HH] = Wpre[tid];
        wpost[tid / HH][tid % HH] = Wpost[tid];
    }
    for (int idx = tid; idx < HH * DD; idx += 256) {
        int h = idx >> 6, d = idx & 63;
        qs[h][d] = Q[((size_t)(b * HH + h) * LL + l) * DD + d];
    }
    __syncthreads();

    for (int idx = tid; idx < HH * LL; idx += 256) {
        int h = idx >> 10, k = idx & 1023;
        const float4* kp4 = (const float4*)(K + ((size_t)(b * HH + h) * LL + k) * DD);
        const float4* qp4 = (const float4*)(qs[h]);
        float ax = 0.f, ay = 0.f, az = 0.f, aw = 0.f;
#pragma unroll
        for (int d4 = 0; d4 < 16; ++d4) {
            float4 kv = kp4[d4];
            float4 qv = qp4[d4];
            ax += qv.x * kv.x; ay += qv.y * kv.y;
            az += qv.z * kv.z; aw += qv.w * kv.w;
        }
        s[h][k] = (ax + ay) + (az + aw);
    }
    __syncthreads();

    for (int k = tid; k < LL; k += 256) {
        float sv[HH], mx[HH];
#pragma unroll
        for (int h = 0; h < HH; ++h) sv[h] = s[h][k];
#pragma unroll
        for (int i = 0; i < HH; ++i) {
            float a = 0.f;
#pragma unroll
            for (int h = 0; h < HH; ++h) a += sv[h] * wpre[h][i];
            mx[i] = a;
        }
#pragma unroll
        for (int i = 0; i < HH; ++i) s[i][k] = mx[i];
    }
    __syncthreads();

    {
        const int wave = tid >> 6;
        const int lane = tid & 63;
        for (int h = wave; h < HH; h += 4) {
            float vals[16];
            float m = -1e30f;
#pragma unroll
            for (int j = 0; j < 16; ++j) {
                vals[j] = s[h][lane + 64 * j];
                m = fmaxf(m, vals[j]);
            }
#pragma unroll
            for (int off = 32; off; off >>= 1) m = fmaxf(m, __shfl_xor(m, off));
            float sum = 0.f;
#pragma unroll
            for (int j = 0; j < 16; ++j) {
                vals[j] = __expf(vals[j] - m);
                sum += vals[j];
            }
#pragma unroll
            for (int off = 32; off; off >>= 1) sum += __shfl_xor(sum, off);
            float inv = 1.0f / sum;
#pragma unroll
            for (int j = 0; j < 16; ++j) s[h][lane + 64 * j] = vals[j] * inv;
        }
    }
    __syncthreads();

    for (int k = tid; k < LL; k += 256) {
        float sv[HH], mx[HH];
#pragma unroll
        for (int h = 0; h < HH; ++h) sv[h] = s[h][k];
#pragma unroll
        for (int i = 0; i < HH; ++i) {
            float a = 0.f;
#pragma unroll
            for (int h = 0; h < HH; ++h) a += sv[h] * wpost[h][i];
            mx[i] = a;
        }
#pragma unroll
        for (int i = 0; i < HH; ++i) s[i][k] = mx[i];
    }
    __syncthreads();

    {
        const int i0 = tid >> 6;
        const int d0 = tid & 63;
        float o0 = 0.f, o1 = 0.f, o2 = 0.f;
        const float* vb = V + (size_t)b * HH * LL * DD;
        const float* v0 = vb + ((size_t)(i0 + 0) * LL) * DD + d0;
        const float* v1 = vb + ((size_t)(i0 + 4) * LL) * DD + d0;
        const float* v2 = vb + ((size_t)(i0 + 8) * LL) * DD + d0;
#pragma unroll 4
        for (int k = 0; k < LL; ++k) {
            o0 += s[i0 + 0][k] * v0[(size_t)k * DD];
            o1 += s[i0 + 4][k] * v1[(size_t)k * DD];
            o2 += s[i0 + 8][k] * v2[(size_t)k * DD];
        }
        float* arow = att + (size_t)(b * LL + l) * CC;
        arow[(i0 + 0) * DD + d0] = o0;
        arow[(i0 + 4) * DD + d0] = o1;
        arow[(i0 + 8) * DD + d0] = o2;
    }
}

// ---------------- Launch ----------------
extern "C" void kernel_launch(void* const* d_in, const int* in_sizes, int n_in,
                              void* d_out, int out_size, void* d_ws, size_t ws_size,
                              hipStream_t stream) {
    const float* inputs_q  = (const float*)d_in[0];
    const float* inputs_kv = (const float*)d_in[1];
    const float* Wq   = (const float*)d_in[2];
    const float* Wk   = (const float*)d_in[3];
    const float* Wv   = (const float*)d_in[4];
    const float* Wout = (const float*)d_in[5];
    const float* Wpre  = (const float*)d_in[6];
    const float* Wpost = (const float*)d_in[7];
    float* out = (float*)d_out;

    const size_t nQKV = (size_t)BB * HH * LL * DD;       // 3,145,728 floats
    const size_t nQKV_b = (size_t)HH * LL * DD;          // per batch: 786,432
    float* Qb  = (float*)d_ws;
    float* Kb  = Qb + nQKV;
    float* Vb  = Kb + nQKV;
    float* Att = Vb + nQKV;
    float* Sb  = Att + nQKV;                             // logits workspace

    const size_t baseBytes   = 4 * nQKV * sizeof(float);          // ~50.3 MB
    const size_t sBatchBytes = (size_t)HH * LL * LL * sizeof(float); // ~50.3 MB

    const int M = BB * LL;   // 4096
    const int Kd = CC;       // 768
    const int N = HH * DD;   // 768

    dim3 gridP(M / Bb_M, N / Bb_N);
    dim3 blk(256);

    const float qscale = 0.125f;  // 1/sqrt(64)
    gemm64<<<gridP, blk, 0, stream>>>(inputs_q,  Wq, Qb, M, Kd, N, qscale, 1);
    gemm64<<<gridP, blk, 0, stream>>>(inputs_kv, Wk, Kb, M, Kd, N, 1.0f, 1);
    gemm64<<<gridP, blk, 0, stream>>>(inputs_kv, Wv, Vb, M, Kd, N, 1.0f, 1);

    if (ws_size >= baseBytes + 4 * sBatchBytes) {
        // all batches at once
        qk_gemm<<<dim3(16, 16, BB * HH), blk, 0, stream>>>(Qb, Kb, Sb);
        mix_softmax<<<dim3(LL, BB), blk, 0, stream>>>(Sb, Wpre, Wpost);
        pv_gemm<<<dim3(16, BB * HH), blk, 0, stream>>>(Sb, Vb, Att);
    } else if (ws_size >= baseBytes + sBatchBytes) {
        // per-batch, shared S buffer
        for (int b = 0; b < BB; ++b) {
            qk_gemm<<<dim3(16, 16, HH), blk, 0, stream>>>(Qb + (size_t)b * nQKV_b,
                                                          Kb + (size_t)b * nQKV_b, Sb);
            mix_softmax<<<dim3(LL, 1), blk, 0, stream>>>(Sb, Wpre, Wpost);
            pv_gemm<<<dim3(16, HH), blk, 0, stream>>>(Sb, Vb + (size_t)b * nQKV_b,
                                                      Att + (size_t)b * LL * CC);
        }
    } else {
        attn_core<<<dim3(BB * LL), blk, 0, stream>>>(Qb, Kb, Vb, Wpre, Wpost, Att);
    }

    gemm64<<<gridP, blk, 0, stream>>>(Att, Wout, out, M, Kd, CC, 1.0f, 0);
}

// Round 3
// 269.743 us; speedup vs baseline: 7.8244x; 2.5040x over previous
//
#include <hip/hip_runtime.h>

#define BB 4
#define LL 1024
#define CC 768
#define HH 12
#define DD 64

typedef unsigned short ushort_t;
typedef __attribute__((ext_vector_type(8))) short bf16x8;
typedef __attribute__((ext_vector_type(4))) float f32x4;

__device__ inline ushort_t f2bf(float x) {
    union { float f; unsigned u; } v; v.f = x;
    unsigned r = (v.u + 0x7FFFu + ((v.u >> 16) & 1u)) >> 16;
    return (ushort_t)r;
}
__device__ inline float bf2f(ushort_t u) {
    union { unsigned u; float f; } v; v.u = ((unsigned)u) << 16;
    return v.f;
}

// ---------------- cast fp32 inputs -> bf16 (elementwise) ----------------
__global__ __launch_bounds__(256) void cast_in(const float* __restrict__ q,
                                               const float* __restrict__ kv,
                                               ushort_t* __restrict__ qo,
                                               ushort_t* __restrict__ kvo) {
    const float* src = blockIdx.y ? kv : q;
    ushort_t* dst = blockIdx.y ? kvo : qo;
    size_t i = ((size_t)blockIdx.x * 256 + threadIdx.x) * 8;
    float4 a = *(const float4*)(src + i);
    float4 b = *(const float4*)(src + i + 4);
    ushort_t t[8] = {f2bf(a.x), f2bf(a.y), f2bf(a.z), f2bf(a.w),
                     f2bf(b.x), f2bf(b.y), f2bf(b.z), f2bf(b.w)};
    *(uint4*)(dst + i) = *(uint4*)t;
}

// ---------------- cast+transpose weights: W[k][n] fp32 -> Wt[n][k] bf16 ----------------
__global__ __launch_bounds__(256) void wt_cast(const float* __restrict__ w0, const float* __restrict__ w1,
                                               const float* __restrict__ w2, const float* __restrict__ w3,
                                               ushort_t* __restrict__ o0, ushort_t* __restrict__ o1,
                                               ushort_t* __restrict__ o2, ushort_t* __restrict__ o3) {
    const float* W = blockIdx.z == 0 ? w0 : blockIdx.z == 1 ? w1 : blockIdx.z == 2 ? w2 : w3;
    ushort_t* Wt   = blockIdx.z == 0 ? o0 : blockIdx.z == 1 ? o1 : blockIdx.z == 2 ? o2 : o3;
    __shared__ float t[32][33];
    const int c = threadIdx.x & 31, r0 = threadIdx.x >> 5;  // c 0..31, r0 0..7
    const int kb = blockIdx.x * 32, nb = blockIdx.y * 32;
#pragma unroll
    for (int i = 0; i < 4; ++i)
        t[r0 + 8 * i][c] = W[(size_t)(kb + r0 + 8 * i) * CC + nb + c];
    __syncthreads();
#pragma unroll
    for (int i = 0; i < 4; ++i)
        Wt[(size_t)(nb + r0 + 8 * i) * CC + kb + c] = f2bf(t[c][r0 + 8 * i]);
}

// ---------------- fused Q/K/V projection (MFMA bf16), z picks target ----------------
// C[4096 x 768] = A[4096 x 768] @ W[768 x 768]; BM=BN=128, BK=32.
// z=0: Q (scale 1/8) -> [b][h][l][d]; z=1: K -> [b][h][l][d]; z=2: V -> [b][h][d][l]
__global__ __launch_bounds__(256) void proj_gemm(const ushort_t* __restrict__ Aq,
                                                 const ushort_t* __restrict__ Akv,
                                                 const ushort_t* __restrict__ Wqt,
                                                 const ushort_t* __restrict__ Wkt,
                                                 const ushort_t* __restrict__ Wvt,
                                                 ushort_t* __restrict__ Qo,
                                                 ushort_t* __restrict__ Ko,
                                                 ushort_t* __restrict__ Vto) {
    const int z = blockIdx.z;
    const ushort_t* A  = (z == 0) ? Aq : Akv;
    const ushort_t* Wt = (z == 0) ? Wqt : (z == 1 ? Wkt : Wvt);

    __shared__ ushort_t a_lds[128 * 40];
    __shared__ ushort_t b_lds[128 * 40];

    const int tid = threadIdx.x;
    const int bm = blockIdx.x * 128, bn = blockIdx.y * 128;
    const int wave = tid >> 6, lane = tid & 63;
    const int quad = lane >> 4, lq = lane & 15;
    const int wr = wave >> 1, wc = wave & 1;

    f32x4 acc[4][4] = {};

    for (int k0 = 0; k0 < CC; k0 += 32) {
#pragma unroll
        for (int s = 0; s < 2; ++s) {
            int c = tid + s * 256;
            int row = c >> 2, ko = (c & 3) * 8;
            *(uint4*)&a_lds[row * 40 + ko] = *(const uint4*)&A[(size_t)(bm + row) * CC + k0 + ko];
            *(uint4*)&b_lds[row * 40 + ko] = *(const uint4*)&Wt[(size_t)(bn + row) * CC + k0 + ko];
        }
        __syncthreads();
        bf16x8 af[4], bfr[4];
#pragma unroll
        for (int mi = 0; mi < 4; ++mi)
            af[mi] = *(bf16x8*)&a_lds[(wr * 64 + mi * 16 + lq) * 40 + quad * 8];
#pragma unroll
        for (int ni = 0; ni < 4; ++ni)
            bfr[ni] = *(bf16x8*)&b_lds[(wc * 64 + ni * 16 + lq) * 40 + quad * 8];
#pragma unroll
        for (int mi = 0; mi < 4; ++mi)
#pragma unroll
            for (int ni = 0; ni < 4; ++ni)
                acc[mi][ni] = __builtin_amdgcn_mfma_f32_16x16x32_bf16(af[mi], bfr[ni], acc[mi][ni], 0, 0, 0);
        __syncthreads();
    }

    const float scale = (z == 0) ? 0.125f : 1.0f;
#pragma unroll
    for (int mi = 0; mi < 4; ++mi)
#pragma unroll
        for (int ni = 0; ni < 4; ++ni)
#pragma unroll
            for (int r = 0; r < 4; ++r) {
                int row = bm + wr * 64 + mi * 16 + quad * 4 + r;  // b*1024+l
                int col = bn + wc * 64 + ni * 16 + lq;            // h*64+d
                int b = row >> 10, l = row & 1023, h = col >> 6, d = col & 63;
                ushort_t v = f2bf(acc[mi][ni][r] * scale);
                if (z == 0)      Qo[((size_t)(b * HH + h) * LL + l) * DD + d] = v;
                else if (z == 1) Ko[((size_t)(b * HH + h) * LL + l) * DD + d] = v;
                else             Vto[((size_t)(b * HH + h) * DD + d) * LL + l] = v;
            }
}

// ---------------- QK^T: S[bh][l][k] bf16 = Q_h[l][d] . K_h[k][d] ----------------
__global__ __launch_bounds__(256) void qk_gemm(const ushort_t* __restrict__ Q,
                                               const ushort_t* __restrict__ K,
                                               ushort_t* __restrict__ S) {
    __shared__ ushort_t a_lds[128 * 40];
    __shared__ ushort_t b_lds[128 * 40];

    const int tid = threadIdx.x;
    const int bm = blockIdx.x * 128, bn = blockIdx.y * 128;
    const int bh = blockIdx.z;
    const ushort_t* Qh = Q + (size_t)bh * LL * DD;
    const ushort_t* Kh = K + (size_t)bh * LL * DD;
    const int wave = tid >> 6, lane = tid & 63;
    const int quad = lane >> 4, lq = lane & 15;
    const int wr = wave >> 1, wc = wave & 1;

    f32x4 acc[4][4] = {};

    for (int k0 = 0; k0 < DD; k0 += 32) {
#pragma unroll
        for (int s = 0; s < 2; ++s) {
            int c = tid + s * 256;
            int row = c >> 2, ko = (c & 3) * 8;
            *(uint4*)&a_lds[row * 40 + ko] = *(const uint4*)&Qh[(size_t)(bm + row) * DD + k0 + ko];
            *(uint4*)&b_lds[row * 40 + ko] = *(const uint4*)&Kh[(size_t)(bn + row) * DD + k0 + ko];
        }
        __syncthreads();
        bf16x8 af[4], bfr[4];
#pragma unroll
        for (int mi = 0; mi < 4; ++mi)
            af[mi] = *(bf16x8*)&a_lds[(wr * 64 + mi * 16 + lq) * 40 + quad * 8];
#pragma unroll
        for (int ni = 0; ni < 4; ++ni)
            bfr[ni] = *(bf16x8*)&b_lds[(wc * 64 + ni * 16 + lq) * 40 + quad * 8];
#pragma unroll
        for (int mi = 0; mi < 4; ++mi)
#pragma unroll
            for (int ni = 0; ni < 4; ++ni)
                acc[mi][ni] = __builtin_amdgcn_mfma_f32_16x16x32_bf16(af[mi], bfr[ni], acc[mi][ni], 0, 0, 0);
        __syncthreads();
    }

#pragma unroll
    for (int mi = 0; mi < 4; ++mi)
#pragma unroll
        for (int ni = 0; ni < 4; ++ni)
#pragma unroll
            for (int r = 0; r < 4; ++r) {
                int row = bm + wr * 64 + mi * 16 + quad * 4 + r;  // l
                int col = bn + wc * 64 + ni * 16 + lq;            // k
                S[((size_t)bh * LL + row) * LL + col] = f2bf(acc[mi][ni][r]);
            }
}

// ---------------- premix -> softmax -> postmix, bf16 in-place ----------------
__global__ __launch_bounds__(256) void mix_softmax(ushort_t* __restrict__ S,
                                                   const float* __restrict__ Wpre,
                                                   const float* __restrict__ Wpost) {
    __shared__ float s[HH][LL];        // 48 KB
    __shared__ float wpre[HH][HH];
    __shared__ float wpost[HH][HH];

    const int tid = threadIdx.x;
    const int l = blockIdx.x;
    const int b = blockIdx.y;

    if (tid < HH * HH) {
        wpre[tid / HH][tid % HH] = Wpre[tid];
        wpost[tid / HH][tid % HH] = Wpost[tid];
    }

    // load 12 rows of 1024 bf16 (128 uint4 chunks per row)
    for (int idx = tid; idx < HH * 128; idx += 256) {
        int h = idx >> 7, c = idx & 127;
        uint4 raw = *(const uint4*)&S[((size_t)(b * HH + h) * LL + l) * LL + c * 8];
        ushort_t* u = (ushort_t*)&raw;
#pragma unroll
        for (int j = 0; j < 8; ++j) s[h][c * 8 + j] = bf2f(u[j]);
    }
    __syncthreads();

    // premix
    for (int k = tid; k < LL; k += 256) {
        float sv[HH], mx[HH];
#pragma unroll
        for (int h = 0; h < HH; ++h) sv[h] = s[h][k];
#pragma unroll
        for (int i = 0; i < HH; ++i) {
            float a = 0.f;
#pragma unroll
            for (int h = 0; h < HH; ++h) a += sv[h] * wpre[h][i];
            mx[i] = a;
        }
#pragma unroll
        for (int i = 0; i < HH; ++i) s[i][k] = mx[i];
    }
    __syncthreads();

    // per-head softmax
    {
        const int wave = tid >> 6;
        const int lane = tid & 63;
        for (int h = wave; h < HH; h += 4) {
            float vals[16];
            float m = -1e30f;
#pragma unroll
            for (int j = 0; j < 16; ++j) {
                vals[j] = s[h][lane + 64 * j];
                m = fmaxf(m, vals[j]);
            }
#pragma unroll
            for (int off = 32; off; off >>= 1) m = fmaxf(m, __shfl_xor(m, off));
            float sum = 0.f;
#pragma unroll
            for (int j = 0; j < 16; ++j) {
                vals[j] = __expf(vals[j] - m);
                sum += vals[j];
            }
#pragma unroll
            for (int off = 32; off; off >>= 1) sum += __shfl_xor(sum, off);
            float inv = 1.0f / sum;
#pragma unroll
            for (int j = 0; j < 16; ++j) s[h][lane + 64 * j] = vals[j] * inv;
        }
    }
    __syncthreads();

    // postmix
    for (int k = tid; k < LL; k += 256) {
        float sv[HH], mx[HH];
#pragma unroll
        for (int h = 0; h < HH; ++h) sv[h] = s[h][k];
#pragma unroll
        for (int i = 0; i < HH; ++i) {
            float a = 0.f;
#pragma unroll
            for (int h = 0; h < HH; ++h) a += sv[h] * wpost[h][i];
            mx[i] = a;
        }
#pragma unroll
        for (int i = 0; i < HH; ++i) s[i][k] = mx[i];
    }
    __syncthreads();

    // store back bf16 in-place (rows owned exclusively by this block)
    for (int idx = tid; idx < HH * 128; idx += 256) {
        int h = idx >> 7, c = idx & 127;
        ushort_t u[8];
#pragma unroll
        for (int j = 0; j < 8; ++j) u[j] = f2bf(s[h][c * 8 + j]);
        *(uint4*)&S[((size_t)(b * HH + h) * LL + l) * LL + c * 8] = *(uint4*)u;
    }
}

// ---------------- PV: att[b*L+l][h*64+d] bf16 = P_h[l][k] . V_h^T[d][k] ----------------
// BM=128, BN=64, BK=32; grid (8, 48)
__global__ __launch_bounds__(256) void pv_gemm(const ushort_t* __restrict__ P,
                                               const ushort_t* __restrict__ Vt,
                                               ushort_t* __restrict__ att) {
    __shared__ ushort_t a_lds[128 * 40];
    __shared__ ushort_t b_lds[64 * 40];

    const int tid = threadIdx.x;
    const int bm = blockIdx.x * 128;
    const int bh = blockIdx.y;
    const int b = bh / HH, ih = bh % HH;
    const ushort_t* Ph = P + ((size_t)bh << 20);
    const ushort_t* Vh = Vt + (size_t)bh * LL * DD;
    const int wave = tid >> 6, lane = tid & 63;
    const int quad = lane >> 4, lq = lane & 15;
    const int wr = wave >> 1, wc = wave & 1;

    f32x4 acc[4][2] = {};

    for (int k0 = 0; k0 < LL; k0 += 32) {
#pragma unroll
        for (int s = 0; s < 2; ++s) {
            int c = tid + s * 256;
            int row = c >> 2, ko = (c & 3) * 8;
            *(uint4*)&a_lds[row * 40 + ko] = *(const uint4*)&Ph[(size_t)(bm + row) * LL + k0 + ko];
        }
        {
            int row = tid >> 2, ko = (tid & 3) * 8;
            *(uint4*)&b_lds[row * 40 + ko] = *(const uint4*)&Vh[(size_t)row * LL + k0 + ko];
        }
        __syncthreads();
        bf16x8 af[4], bfr[2];
#pragma unroll
        for (int mi = 0; mi < 4; ++mi)
            af[mi] = *(bf16x8*)&a_lds[(wr * 64 + mi * 16 + lq) * 40 + quad * 8];
#pragma unroll
        for (int ni = 0; ni < 2; ++ni)
            bfr[ni] = *(bf16x8*)&b_lds[(wc * 32 + ni * 16 + lq) * 40 + quad * 8];
#pragma unroll
        for (int mi = 0; mi < 4; ++mi)
#pragma unroll
            for (int ni = 0; ni < 2; ++ni)
                acc[mi][ni] = __builtin_amdgcn_mfma_f32_16x16x32_bf16(af[mi], bfr[ni], acc[mi][ni], 0, 0, 0);
        __syncthreads();
    }

#pragma unroll
    for (int mi = 0; mi < 4; ++mi)
#pragma unroll
        for (int ni = 0; ni < 2; ++ni)
#pragma unroll
            for (int r = 0; r < 4; ++r) {
                int lrow = bm + wr * 64 + mi * 16 + quad * 4 + r;
                int col = wc * 32 + ni * 16 + lq;  // d
                att[((size_t)(b * LL) + lrow) * CC + ih * DD + col] = f2bf(acc[mi][ni][r]);
            }
}

// ---------------- out = att @ Wout (MFMA, fp32 out) ----------------
__global__ __launch_bounds__(256) void out_gemm(const ushort_t* __restrict__ A,
                                                const ushort_t* __restrict__ Wt,
                                                float* __restrict__ out) {
    __shared__ ushort_t a_lds[128 * 40];
    __shared__ ushort_t b_lds[128 * 40];

    const int tid = threadIdx.x;
    const int bm = blockIdx.x * 128, bn = blockIdx.y * 128;
    const int wave = tid >> 6, lane = tid & 63;
    const int quad = lane >> 4, lq = lane & 15;
    const int wr = wave >> 1, wc = wave & 1;

    f32x4 acc[4][4] = {};

    for (int k0 = 0; k0 < CC; k0 += 32) {
#pragma unroll
        for (int s = 0; s < 2; ++s) {
            int c = tid + s * 256;
            int row = c >> 2, ko = (c & 3) * 8;
            *(uint4*)&a_lds[row * 40 + ko] = *(const uint4*)&A[(size_t)(bm + row) * CC + k0 + ko];
            *(uint4*)&b_lds[row * 40 + ko] = *(const uint4*)&Wt[(size_t)(bn + row) * CC + k0 + ko];
        }
        __syncthreads();
        bf16x8 af[4], bfr[4];
#pragma unroll
        for (int mi = 0; mi < 4; ++mi)
            af[mi] = *(bf16x8*)&a_lds[(wr * 64 + mi * 16 + lq) * 40 + quad * 8];
#pragma unroll
        for (int ni = 0; ni < 4; ++ni)
            bfr[ni] = *(bf16x8*)&b_lds[(wc * 64 + ni * 16 + lq) * 40 + quad * 8];
#pragma unroll
        for (int mi = 0; mi < 4; ++mi)
#pragma unroll
            for (int ni = 0; ni < 4; ++ni)
                acc[mi][ni] = __builtin_amdgcn_mfma_f32_16x16x32_bf16(af[mi], bfr[ni], acc[mi][ni], 0, 0, 0);
        __syncthreads();
    }

#pragma unroll
    for (int mi = 0; mi < 4; ++mi)
#pragma unroll
        for (int ni = 0; ni < 4; ++ni)
#pragma unroll
            for (int r = 0; r < 4; ++r) {
                int row = bm + wr * 64 + mi * 16 + quad * 4 + r;
                int col = bn + wc * 64 + ni * 16 + lq;
                out[(size_t)row * CC + col] = acc[mi][ni][r];
            }
}

// ---------------- Launch ----------------
extern "C" void kernel_launch(void* const* d_in, const int* in_sizes, int n_in,
                              void* d_out, int out_size, void* d_ws, size_t ws_size,
                              hipStream_t stream) {
    const float* inputs_q  = (const float*)d_in[0];
    const float* inputs_kv = (const float*)d_in[1];
    const float* Wq   = (const float*)d_in[2];
    const float* Wk   = (const float*)d_in[3];
    const float* Wv   = (const float*)d_in[4];
    const float* Wout = (const float*)d_in[5];
    const float* Wpre  = (const float*)d_in[6];
    const float* Wpost = (const float*)d_in[7];
    float* out = (float*)d_out;

    const size_t nS   = (size_t)BB * HH * LL * LL;   // 50,331,648 bf16
    const size_t nQKV = (size_t)BB * HH * LL * DD;   // 3,145,728 bf16
    const size_t nW   = (size_t)CC * CC;             // 589,824 bf16

    ushort_t* Sb   = (ushort_t*)d_ws;
    ushort_t* Qb   = Sb + nS;
    ushort_t* Kb   = Qb + nQKV;
    ushort_t* Vtb  = Kb + nQKV;
    ushort_t* attb = Vtb + nQKV;
    ushort_t* inq  = attb + nQKV;
    ushort_t* inkv = inq + nQKV;
    ushort_t* Wqt  = inkv + nQKV;
    ushort_t* Wkt  = Wqt + nW;
    ushort_t* Wvt  = Wkt + nW;
    ushort_t* Wot  = Wvt + nW;

    dim3 blk(256);

    cast_in<<<dim3(1536, 2), blk, 0, stream>>>(inputs_q, inputs_kv, inq, inkv);
    wt_cast<<<dim3(24, 24, 4), blk, 0, stream>>>(Wq, Wk, Wv, Wout, Wqt, Wkt, Wvt, Wot);
    proj_gemm<<<dim3(32, 6, 3), blk, 0, stream>>>(inq, inkv, Wqt, Wkt, Wvt, Qb, Kb, Vtb);
    qk_gemm<<<dim3(8, 8, BB * HH), blk, 0, stream>>>(Qb, Kb, Sb);
    mix_softmax<<<dim3(LL, BB), blk, 0, stream>>>(Sb, Wpre, Wpost);
    pv_gemm<<<dim3(8, BB * HH), blk, 0, stream>>>(Sb, Vtb, attb);
    out_gemm<<<dim3(32, 6), blk, 0, stream>>>(attb, Wot, out);
}